// Round 1
// baseline (790.724 us; speedup 1.0000x reference)
//
#include <hip/hip_runtime.h>
#include <hip/hip_bf16.h>
#include <cstdint>

// MoRALinear: out[m,o] = sum_i x[m,i] * (W[o,i] + A[o&1023, i&1023]) + b[o]
//   (the MoRA fold/tile structure folds exactly into the weight matrix)
// Strategy:
//   prep1: x   (fp32 [16384,4096]) -> bf16, tiled [mb][kb][128][64] in ws
//   prep2: W+A (fp32)              -> bf16, tiled [nb][kb][128][64] in ws
//   gemm : 128x128x(K=64-step) bf16 MFMA 16x16x32, m97-structure
//          (global_load_lds width 16, 2 barriers/K-step), epilogue adds bias.

typedef __attribute__((ext_vector_type(8))) short bf16x8;
typedef __attribute__((ext_vector_type(4))) float f32x4;
typedef __attribute__((ext_vector_type(4))) float fvec4;

static constexpr int MTOT = 16384;   // B*S
static constexpr int KF   = 4096;    // IN_F
static constexpr int NF   = 4096;    // OUT_F
static constexpr int BM = 128, BN = 128, BK = 64;
static constexpr int TILE_ELEMS = BM * BK;          // 8192 bf16 per staged tile
static constexpr int KTILES = KF / BK;              // 64

// ---------------- prep: x -> bf16 tiled ----------------
__global__ __launch_bounds__(256) void tile_x_kernel(const float* __restrict__ x,
                                                     __hip_bfloat16* __restrict__ xt) {
    int tile = blockIdx.x;              // mb*KTILES + kb ; grid = 128*64
    int mb = tile >> 6, kb = tile & 63;
    int t = threadIdx.x;
    const float* src = x + (size_t)mb * BM * KF + (size_t)kb * BK;
    __hip_bfloat16* dst = xt + (size_t)tile * TILE_ELEMS;
#pragma unroll
    for (int it = 0; it < 4; ++it) {
        int e = (it * 256 + t) * 8;     // element within tile
        int r = e >> 6, k = e & 63;
        const fvec4* s = (const fvec4*)(src + (size_t)r * KF + k);
        fvec4 v0 = s[0], v1 = s[1];
        union { bf16x8 v; __hip_bfloat16 h[8]; } o;
        o.h[0] = __float2bfloat16(v0[0]); o.h[1] = __float2bfloat16(v0[1]);
        o.h[2] = __float2bfloat16(v0[2]); o.h[3] = __float2bfloat16(v0[3]);
        o.h[4] = __float2bfloat16(v1[0]); o.h[5] = __float2bfloat16(v1[1]);
        o.h[6] = __float2bfloat16(v1[2]); o.h[7] = __float2bfloat16(v1[3]);
        *(bf16x8*)(dst + e) = o.v;
    }
}

// ---------------- prep: W' = W + tiled(A) -> bf16 tiled ----------------
__global__ __launch_bounds__(256) void tile_w_kernel(const float* __restrict__ W,
                                                     const float* __restrict__ A,
                                                     __hip_bfloat16* __restrict__ wt) {
    int tile = blockIdx.x;              // nb*KTILES + kb ; grid = 32*64
    int nb = tile >> 6, kb = tile & 63;
    int t = threadIdx.x;
    const float* srcW = W + (size_t)nb * BN * KF + (size_t)kb * BK;
    __hip_bfloat16* dst = wt + (size_t)tile * TILE_ELEMS;
#pragma unroll
    for (int it = 0; it < 4; ++it) {
        int e = (it * 256 + t) * 8;
        int r = e >> 6, k = e & 63;
        int o = nb * BN + r;            // out-feature index
        int i0 = kb * BK + k;           // in-feature index (multiple of 8)
        const fvec4* sw = (const fvec4*)(srcW + (size_t)r * KF + k);
        const fvec4* sa = (const fvec4*)(A + (size_t)(o & 1023) * 1024 + (i0 & 1023));
        fvec4 w0 = sw[0], w1 = sw[1];
        fvec4 a0 = sa[0], a1 = sa[1];
        union { bf16x8 v; __hip_bfloat16 h[8]; } ov;
        ov.h[0] = __float2bfloat16(w0[0] + a0[0]); ov.h[1] = __float2bfloat16(w0[1] + a0[1]);
        ov.h[2] = __float2bfloat16(w0[2] + a0[2]); ov.h[3] = __float2bfloat16(w0[3] + a0[3]);
        ov.h[4] = __float2bfloat16(w1[0] + a1[0]); ov.h[5] = __float2bfloat16(w1[1] + a1[1]);
        ov.h[6] = __float2bfloat16(w1[2] + a1[2]); ov.h[7] = __float2bfloat16(w1[3] + a1[3]);
        *(bf16x8*)(dst + e) = ov.v;
    }
}

// ---------------- async global->LDS helper (width 16) ----------------
__device__ inline void gload_lds16(const __hip_bfloat16* g, __hip_bfloat16* l) {
    __builtin_amdgcn_global_load_lds(
        (const __attribute__((address_space(1))) unsigned int*)g,
        (__attribute__((address_space(3))) unsigned int*)l, 16, 0, 0);
}

// ---------------- main GEMM: out = xt @ wt^T + bias ----------------
__global__ __launch_bounds__(256) void gemm_bf16_kernel(
    const __hip_bfloat16* __restrict__ xt, const __hip_bfloat16* __restrict__ wt,
    const float* __restrict__ bias, float* __restrict__ out) {
    __shared__ __hip_bfloat16 As[TILE_ELEMS];
    __shared__ __hip_bfloat16 Bs[TILE_ELEMS];

    // XCD-aware swizzle: nwg = 4096 (divisible by 8) -> contiguous chunks/XCD
    int bid = blockIdx.x;
    int wg  = (bid & 7) * 512 + (bid >> 3);
    int mb = wg >> 5;                   // 128 row-blocks
    int nb = wg & 31;                   // 32 col-blocks

    int t = threadIdx.x;
    int lane = t & 63;
    int wv = t >> 6;                    // wave id 0..3
    int wm = wv >> 1, wn = wv & 1;      // 2x2 wave grid, 64x64 out each
    int lr = lane & 15;                 // fragment row/col
    int lk = (lane >> 4) * 8;           // fragment k base

    f32x4 acc[4][4];
#pragma unroll
    for (int m = 0; m < 4; ++m)
#pragma unroll
        for (int n = 0; n < 4; ++n) acc[m][n] = f32x4{0.f, 0.f, 0.f, 0.f};

    const __hip_bfloat16* aPanel = xt + (size_t)mb * KTILES * TILE_ELEMS;
    const __hip_bfloat16* bPanel = wt + (size_t)nb * KTILES * TILE_ELEMS;

    for (int kt = 0; kt < KTILES; ++kt) {
        const __hip_bfloat16* ga = aPanel + (size_t)kt * TILE_ELEMS + t * 8;
        const __hip_bfloat16* gb = bPanel + (size_t)kt * TILE_ELEMS + t * 8;
#pragma unroll
        for (int i = 0; i < 4; ++i) {
            gload_lds16(ga + i * 2048, As + t * 8 + i * 2048);
            gload_lds16(gb + i * 2048, Bs + t * 8 + i * 2048);
        }
        __syncthreads();                 // compiler drains vmcnt before barrier
#pragma unroll
        for (int kk = 0; kk < BK; kk += 32) {
            bf16x8 af[4], bfr[4];
#pragma unroll
            for (int m = 0; m < 4; ++m)
                af[m] = *(const bf16x8*)(As + (wm * 64 + m * 16 + lr) * BK + kk + lk);
#pragma unroll
            for (int n = 0; n < 4; ++n)
                bfr[n] = *(const bf16x8*)(Bs + (wn * 64 + n * 16 + lr) * BK + kk + lk);
#pragma unroll
            for (int m = 0; m < 4; ++m)
#pragma unroll
                for (int n = 0; n < 4; ++n)
                    acc[m][n] = __builtin_amdgcn_mfma_f32_16x16x32_bf16(
                        af[m], bfr[n], acc[m][n], 0, 0, 0);
        }
        __syncthreads();
    }

    // epilogue: C/D layout col = lane&15, row = (lane>>4)*4 + j
    int row0 = mb * BM + wm * 64;
    int col0 = nb * BN + wn * 64;
#pragma unroll
    for (int n = 0; n < 4; ++n) {
        int col = col0 + n * 16 + lr;
        float bv = bias[col];
#pragma unroll
        for (int m = 0; m < 4; ++m) {
            int row = row0 + m * 16 + (lane >> 4) * 4;
#pragma unroll
            for (int j = 0; j < 4; ++j)
                out[(size_t)(row + j) * NF + col] = acc[m][n][j] + bv;
        }
    }
}

extern "C" void kernel_launch(void* const* d_in, const int* in_sizes, int n_in,
                              void* d_out, int out_size, void* d_ws, size_t ws_size,
                              hipStream_t stream) {
    const float* x = (const float*)d_in[0];
    const float* W = (const float*)d_in[1];
    const float* b = (const float*)d_in[2];
    const float* A = (const float*)d_in[3];
    float* out = (float*)d_out;

    size_t xt_elems = (size_t)MTOT * KF;            // 128 MB as bf16
    size_t wt_elems = (size_t)NF * KF;              // 32 MB as bf16
    size_t need = (xt_elems + wt_elems) * sizeof(__hip_bfloat16);
    if (ws_size < need) return;                     // loud failure (poisoned out)

    __hip_bfloat16* xt = (__hip_bfloat16*)d_ws;
    __hip_bfloat16* wt = xt + xt_elems;

    tile_x_kernel<<<(MTOT / BM) * KTILES, 256, 0, stream>>>(x, xt);
    tile_w_kernel<<<(NF / BN) * KTILES, 256, 0, stream>>>(W, A, wt);
    gemm_bf16_kernel<<<(MTOT / BM) * (NF / BN), 256, 0, stream>>>(xt, wt, b, out);
}

// Round 4
// 606.354 us; speedup vs baseline: 1.3041x; 1.3041x over previous
//
#include <hip/hip_runtime.h>
#include <hip/hip_bf16.h>
#include <cstdint>

// MoRALinear: out[m,o] = sum_i x[m,i] * (W[o,i] + A[o&1023, i&1023]) + b[o]
// R4: 256x256 tile, BK=32, 8-wave, 4-slot LDS ring, counted vmcnt(4),
//     FRAGMENT-MAJOR ws panels: per (mb|nb,kt) tile = 16 fragments x 512 elems,
//     elem(f*512 + lane*8 + j) = M[f*16 + (lane&15)][kt*32 + (lane>>4)*8 + j].
//     -> global_load_lds stages linearly; every ds_read_b128 is base+lane*16B
//     (conflict-free by construction). setprio around MFMA, XCD-chunked order.

typedef __attribute__((ext_vector_type(8))) short bf16x8;
typedef __attribute__((ext_vector_type(4))) float f32x4;
typedef __attribute__((ext_vector_type(4))) float fvec4;

static constexpr int MTOT = 16384;   // B*S
static constexpr int KF   = 4096;    // IN_F
static constexpr int NF   = 4096;    // OUT_F
static constexpr int BM = 256, BN = 256, BK = 32;
static constexpr int TILE = BM * BK;          // 8192 bf16 elems per K-tile panel
static constexpr int KT = KF / BK;            // 128 K-tiles
static constexpr int MB = MTOT / BM;          // 64
static constexpr int NB = NF / BN;            // 16

// ---------------- prep: x -> bf16, fragment-major [mb][kt][f][lane][8] -------
__global__ __launch_bounds__(256) void tile_x_kernel(const float* __restrict__ x,
                                                     __hip_bfloat16* __restrict__ xt) {
    int blk = blockIdx.x;               // mb*KT + kt ; grid = 64*128
    int mb = blk >> 7, kt = blk & 127;
    int tid = threadIdx.x;
    __hip_bfloat16* dst = xt + (size_t)blk * TILE;
#pragma unroll
    for (int it = 0; it < 4; ++it) {
        int e = (it * 256 + tid) * 8;   // element within tile, 0..8191
        int f = e >> 9;                 // fragment 0..15
        int l = (e >> 3) & 63;          // lane 0..63
        int row = mb * BM + f * 16 + (l & 15);
        int k0  = kt * BK + (l >> 4) * 8;          // (l>>4) in 0..3 -> k off 0..24
        const fvec4* s = (const fvec4*)(x + (size_t)row * KF + k0);
        fvec4 v0 = s[0], v1 = s[1];
        union { bf16x8 v; __hip_bfloat16 h[8]; } o;
        o.h[0] = __float2bfloat16(v0[0]); o.h[1] = __float2bfloat16(v0[1]);
        o.h[2] = __float2bfloat16(v0[2]); o.h[3] = __float2bfloat16(v0[3]);
        o.h[4] = __float2bfloat16(v1[0]); o.h[5] = __float2bfloat16(v1[1]);
        o.h[6] = __float2bfloat16(v1[2]); o.h[7] = __float2bfloat16(v1[3]);
        *(bf16x8*)(dst + e) = o.v;
    }
}

// ---------------- prep: W' = W + tiled(A) -> bf16 fragment-major -------------
__global__ __launch_bounds__(256) void tile_w_kernel(const float* __restrict__ W,
                                                     const float* __restrict__ A,
                                                     __hip_bfloat16* __restrict__ wt) {
    int blk = blockIdx.x;               // nb*KT + kt ; grid = 16*128
    int nb = blk >> 7, kt = blk & 127;
    int tid = threadIdx.x;
    __hip_bfloat16* dst = wt + (size_t)blk * TILE;
#pragma unroll
    for (int it = 0; it < 4; ++it) {
        int e = (it * 256 + tid) * 8;
        int f = e >> 9;
        int l = (e >> 3) & 63;
        int o  = nb * BN + f * 16 + (l & 15);
        int k0 = kt * BK + (l >> 4) * 8;
        const fvec4* sw = (const fvec4*)(W + (size_t)o * KF + k0);
        const fvec4* sa = (const fvec4*)(A + (size_t)(o & 1023) * 1024 + (k0 & 1023));
        fvec4 w0 = sw[0], w1 = sw[1];
        fvec4 a0 = sa[0], a1 = sa[1];
        union { bf16x8 v; __hip_bfloat16 h[8]; } ov;
        ov.h[0] = __float2bfloat16(w0[0] + a0[0]); ov.h[1] = __float2bfloat16(w0[1] + a0[1]);
        ov.h[2] = __float2bfloat16(w0[2] + a0[2]); ov.h[3] = __float2bfloat16(w0[3] + a0[3]);
        ov.h[4] = __float2bfloat16(w1[0] + a1[0]); ov.h[5] = __float2bfloat16(w1[1] + a1[1]);
        ov.h[6] = __float2bfloat16(w1[2] + a1[2]); ov.h[7] = __float2bfloat16(w1[3] + a1[7 - 7 + 3]);
        *(bf16x8*)(dst + e) = ov.v;
    }
}

// ---------------- async global->LDS (width 16) ----------------
__device__ inline void gload_lds16(const __hip_bfloat16* g, __hip_bfloat16* l) {
    __builtin_amdgcn_global_load_lds(
        (const __attribute__((address_space(1))) unsigned int*)g,
        (__attribute__((address_space(3))) unsigned int*)l, 16, 0, 0);
}

// stage helpers: 2 global_load_lds per part (A or B panel) = 16 KB per part
#define STG_A(tt, sl) { const __hip_bfloat16* g = aP + (size_t)(tt) * TILE;      \
    gload_lds16(g, As + (sl) * TILE + t8);                                       \
    gload_lds16(g + 4096, As + (sl) * TILE + 4096 + t8); }
#define STG_B(tt, sl) { const __hip_bfloat16* g = bP + (size_t)(tt) * TILE;      \
    gload_lds16(g, Bs + (sl) * TILE + t8);                                       \
    gload_lds16(g + 4096, Bs + (sl) * TILE + 4096 + t8); }

#define ENDP {                                                                   \
    asm volatile("" ::: "memory");                                               \
    __builtin_amdgcn_s_barrier();                                                \
    asm volatile("" ::: "memory"); }

#define ENDP_W4 {                                                                \
    asm volatile("s_waitcnt vmcnt(4)" ::: "memory");                             \
    __builtin_amdgcn_s_barrier();                                                \
    asm volatile("" ::: "memory"); }

// one phase: ds-reads (frag-major: base + lane*16B), stage issue, barrier,
// 16 MFMA under setprio.  A fragment (wm*8+PH*4+m): off = wm*4096+PH*2048+m*512.
// B fragment (wn*4+n): off = wn*2048+n*512.
#define PHASE(SL, PH, DOB, STAGE_STMT) {                                         \
    bf16x8 af[4];                                                                \
    {                                                                            \
        const __hip_bfloat16* ab = As + (SL) * TILE + aOff + (PH) * 2048;        \
        af[0] = *(const bf16x8*)(ab);                                            \
        af[1] = *(const bf16x8*)(ab + 512);                                      \
        af[2] = *(const bf16x8*)(ab + 1024);                                     \
        af[3] = *(const bf16x8*)(ab + 1536);                                     \
        if (DOB) {                                                               \
            const __hip_bfloat16* bb = Bs + (SL) * TILE + bOff;                  \
            bfr[0] = *(const bf16x8*)(bb);                                       \
            bfr[1] = *(const bf16x8*)(bb + 512);                                 \
            bfr[2] = *(const bf16x8*)(bb + 1024);                                \
            bfr[3] = *(const bf16x8*)(bb + 1536);                                \
        }                                                                        \
    }                                                                            \
    STAGE_STMT;                                                                  \
    asm volatile("" ::: "memory");                                               \
    __builtin_amdgcn_s_barrier();                                                \
    asm volatile("" ::: "memory");                                               \
    __builtin_amdgcn_s_setprio(1);                                               \
    _Pragma("unroll") for (int m = 0; m < 4; ++m)                                \
        _Pragma("unroll") for (int n = 0; n < 4; ++n)                            \
            acc[(PH) * 4 + m][n] = __builtin_amdgcn_mfma_f32_16x16x32_bf16(      \
                af[m], bfr[n], acc[(PH) * 4 + m][n], 0, 0, 0);                   \
    __builtin_amdgcn_s_setprio(0); }

__global__ __launch_bounds__(512, 2) void gemm_bf16_kernel(
    const __hip_bfloat16* __restrict__ xt, const __hip_bfloat16* __restrict__ wt,
    const float* __restrict__ bias, float* __restrict__ out) {
    extern __shared__ __hip_bfloat16 lds[];
    __hip_bfloat16* As = lds;                 // 4 slots * 8192
    __hip_bfloat16* Bs = lds + 4 * TILE;      // 4 slots * 8192

    // XCD chunking, nb-major inside chunk: each XCD holds 2 B-panels (L2-resident)
    int bid = blockIdx.x;                     // nwg = 1024
    int wg = (bid & 7) * 128 + (bid >> 3);
    int nb = wg >> 6;                         // 16 col-blocks
    int mb = wg & 63;                         // 64 row-blocks

    int tid = threadIdx.x;
    int lane = tid & 63;
    int wv = tid >> 6;                        // 8 waves
    int wm = wv >> 2, wn = wv & 3;            // 2 x 4 wave grid, 128x64 C each
    int lr = lane & 15;
    int hi = lane >> 4;
    int t8 = tid * 8;

    int aOff = wm * 4096 + lane * 8;          // + PH*2048 + m*512
    int bOff = wn * 2048 + lane * 8;          // + n*512

    const __hip_bfloat16* aP = xt + (size_t)mb * (KT * TILE) + t8;
    const __hip_bfloat16* bP = wt + (size_t)nb * (KT * TILE) + t8;

    f32x4 acc[8][4];
#pragma unroll
    for (int m = 0; m < 8; ++m)
#pragma unroll
        for (int n = 0; n < 4; ++n) acc[m][n] = f32x4{0.f, 0.f, 0.f, 0.f};
    bf16x8 bfr[4];

    // prologue: tiles 0,1,2 -> slots 0,1,2 (12 loads); drain tiles 0,1
    STG_A(0, 0); STG_B(0, 0);
    STG_A(1, 1); STG_B(1, 1);
    STG_A(2, 2); STG_B(2, 2);
    ENDP_W4

    // main loop: 32 iters x 4 K-tiles; issue tile u+3 during tile u;
    // vmcnt(4) at ends of odd K-tiles keeps exactly 1 tile (4 loads) in flight.
    for (int j = 0; j < KT / 4; ++j) {
        int tb = 4 * j;
        int t4 = tb + 4; if (t4 >= KT) t4 = 0;   // tail: clamp source (slot unused)
        int t5 = tb + 5; if (t5 >= KT) t5 = 0;
        int t6 = tb + 6; if (t6 >= KT) t6 = 0;
        PHASE(0, 0, 1, STG_A(tb + 3, 3)); ENDP
        PHASE(0, 1, 0, STG_B(tb + 3, 3)); ENDP
        PHASE(1, 0, 1, STG_A(t4, 0));     ENDP
        PHASE(1, 1, 0, STG_B(t4, 0));     ENDP_W4
        PHASE(2, 0, 1, STG_A(t5, 1));     ENDP
        PHASE(2, 1, 0, STG_B(t5, 1));     ENDP
        PHASE(3, 0, 1, STG_A(t6, 2));     ENDP
        PHASE(3, 1, 0, STG_B(t6, 2));     ENDP_W4
    }
    // drain all LDS-DMA before kernel end (no in-flight writes at s_endpgm)
    asm volatile("s_waitcnt vmcnt(0)" ::: "memory");

    // epilogue: C/D layout col = lane&15, row = (lane>>4)*4 + jj
    int row0 = mb * BM + wm * 128;
    int col0 = nb * BN + wn * 64;
#pragma unroll
    for (int n = 0; n < 4; ++n) {
        int col = col0 + n * 16 + lr;
        float bv = bias[col];
#pragma unroll
        for (int mf = 0; mf < 8; ++mf) {
            int row = row0 + mf * 16 + hi * 4;
#pragma unroll
            for (int jj = 0; jj < 4; ++jj)
                out[(size_t)(row + jj) * NF + col] = acc[mf][n][jj] + bv;
        }
    }
}

extern "C" void kernel_launch(void* const* d_in, const int* in_sizes, int n_in,
                              void* d_out, int out_size, void* d_ws, size_t ws_size,
                              hipStream_t stream) {
    const float* x = (const float*)d_in[0];
    const float* W = (const float*)d_in[1];
    const float* b = (const float*)d_in[2];
    const float* A = (const float*)d_in[3];
    float* out = (float*)d_out;

    size_t xt_elems = (size_t)MB * KT * TILE;       // 67.1M elems
    size_t wt_elems = (size_t)NB * KT * TILE;       // 16.8M elems
    size_t need = (xt_elems + wt_elems) * sizeof(__hip_bfloat16);
    if (ws_size < need) return;

    __hip_bfloat16* xt = (__hip_bfloat16*)d_ws;
    __hip_bfloat16* wt = xt + xt_elems;

    (void)hipFuncSetAttribute((const void*)gemm_bf16_kernel,
                              hipFuncAttributeMaxDynamicSharedMemorySize, 131072);

    tile_x_kernel<<<MB * KT, 256, 0, stream>>>(x, xt);
    tile_w_kernel<<<NB * KT, 256, 0, stream>>>(W, A, wt);
    gemm_bf16_kernel<<<MB * NB, 512, 131072, stream>>>(xt, wt, b, out);
}